// Round 16
// baseline (165.964 us; speedup 1.0000x reference)
//
#include <hip/hip_runtime.h>
#include <hip/hip_bf16.h>

#define PP   512
#define CC   32
#define HWD  3072           // 64*48
#define PDIMK 34
#define NIMG 32
#define NCH  (HWD / 256)    // 12 K-chunks of 256 floats

static constexpr float INV_NORM  = 1.0f / 96.0f;
static constexpr float INV_PNORM = 1.0f / 480.0f;

typedef short bf16x8 __attribute__((ext_vector_type(8)));
typedef float f32x4  __attribute__((ext_vector_type(4)));

__device__ __forceinline__ short f2bf(float f) {   // RNE fp32 -> bf16 bits
    __hip_bfloat16 h = __float2bfloat16(f);
    return *reinterpret_cast<short*>(&h);
}

// async global->LDS, 16B per lane: dest = lds + lane*16 (linear), src per-lane
__device__ __forceinline__ void gload_lds16(const float* g, float* l) {
    __builtin_amdgcn_global_load_lds(
        (const __attribute__((address_space(1))) void*)g,
        (__attribute__((address_space(3))) void*)l, 16, 0, 0);
}

// workspace int layout:
// [0..32] gstart  [33] npairs  [64..575] start[i]  [576..1087] cnt[i]
// [1088..1599] pairBase[i]   byte 8192+: rel/att buffer [c][strideP] floats

__global__ void k_groups(const int* __restrict__ imgid, int* __restrict__ wsI) {
    __shared__ int s_img[PP];
    __shared__ int s_cnt[PP];
    int t = threadIdx.x;
    s_img[t] = imgid[t];
    __syncthreads();
    int v = s_img[t];
    int lo = 0, hi = PP;
    while (lo < hi) { int mid = (lo + hi) >> 1; if (s_img[mid] < v) lo = mid + 1; else hi = mid; }
    int st = lo;
    lo = 0; hi = PP;
    while (lo < hi) { int mid = (lo + hi) >> 1; if (s_img[mid] <= v) lo = mid + 1; else hi = mid; }
    int cn = lo - st;
    wsI[64 + t]  = st;
    wsI[576 + t] = cn;
    s_cnt[t] = cn;
    if (t <= NIMG) {
        lo = 0; hi = PP;
        while (lo < hi) { int mid = (lo + hi) >> 1; if (s_img[mid] < t) lo = mid + 1; else hi = mid; }
        wsI[t] = lo;
    }
    __syncthreads();
    if (t == 0) {
        int acc = 0;
        for (int i = 0; i < PP; ++i) { wsI[1088 + i] = acc; acc += s_cnt[i]; }
        wsI[33] = acc;
    }
}

// rel[c][p(i,j)] = dot(x[c,i,:], x[c,j,:]) / 96   (transposed layout)
// global_load_lds staging (dense 1KB/row bursts, fire-and-forget), XOR-swizzle
// applied to SOURCE (linear LDS dest) and to frag reads -> conflict-free.
// K split across 4 waves (one f32x4 acc per tile per wave), LDS reduce.
// Grid (image, channel), block 256 = 4 waves.
__global__ __launch_bounds__(256) void k_rel(const float* __restrict__ feats,
                                             const int* __restrict__ wsI,
                                             float* __restrict__ relbuf, int strideP) {
    __shared__ float buf[2][32 * 256];   // 64 KB (2 chunks x 32 rows x 1KB)
    __shared__ f32x4 red[3][4][64];      // 12 KB reduce scratch
    int m = blockIdx.x, c = blockIdx.y;
    int g0 = wsI[m], n = wsI[m + 1] - g0;
    if (n <= 0) return;
    const int* pairBase = wsI + 1088;
    int t = threadIdx.x, wave = t >> 6, lane = t & 63;
    int fr = lane & 15, fq = lane >> 4;
    const size_t rstride = (size_t)CC * HWD;
    const float* base = feats + ((size_t)g0 * CC + c) * HWD;
    int nt = (n + 15) >> 4;
    int s = fr & 7;                       // read-side XOR (row&7; (16+fr)&7 == fr&7)

    if (nt == 1) {
        f32x4 acc = {0.f, 0.f, 0.f, 0.f};
        for (int rr = 0; rr < 4; ++rr) {
            int r = wave * 4 + rr;
            if (r < n) gload_lds16(base + (size_t)r * rstride + ((lane ^ (r & 7)) << 2),
                                   &buf[0][r * 256]);
        }
        __syncthreads();
        for (int ch = 0; ch < NCH; ++ch) {
            int cur = ch & 1;
            if (ch + 1 < NCH) {
                int kc = (ch + 1) * 256;
                for (int rr = 0; rr < 4; ++rr) {
                    int r = wave * 4 + rr;
                    if (r < n) gload_lds16(base + (size_t)r * rstride + kc + ((lane ^ (r & 7)) << 2),
                                           &buf[cur ^ 1][r * 256]);
                }
            }
#pragma unroll
            for (int k2 = 0; k2 < 2; ++k2) {
                int q0 = (wave * 2 + k2) * 8 + fq * 2;
                float4 f0 = *(const float4*)&buf[cur][fr * 256 + ((q0 ^ s) << 2)];
                float4 f1 = *(const float4*)&buf[cur][fr * 256 + (((q0 + 1) ^ s) << 2)];
                bf16x8 af = { f2bf(f0.x), f2bf(f0.y), f2bf(f0.z), f2bf(f0.w),
                              f2bf(f1.x), f2bf(f1.y), f2bf(f1.z), f2bf(f1.w) };
                acc = __builtin_amdgcn_mfma_f32_16x16x32_bf16(af, af, acc, 0, 0, 0);
            }
            __syncthreads();
        }
        red[0][wave][lane] = acc;
        __syncthreads();
        if (wave == 0) {
            f32x4 s4 = red[0][0][lane] + red[0][1][lane] + red[0][2][lane] + red[0][3][lane];
#pragma unroll
            for (int q = 0; q < 4; ++q) {
                int i = fq * 4 + q, j = fr;          // C/D map (HW-verified)
                if (i < n && j < n) {
                    int p = pairBase[g0 + i] + j;
                    if (p < strideP) relbuf[(size_t)c * strideP + p] = s4[q] * INV_NORM;
                }
            }
        }
    } else if (nt == 2) {
        f32x4 a00 = {0.f,0.f,0.f,0.f}, a01 = a00, a11 = a00;
        for (int rr = 0; rr < 8; ++rr) {
            int r = wave * 8 + rr;
            if (r < n) gload_lds16(base + (size_t)r * rstride + ((lane ^ (r & 7)) << 2),
                                   &buf[0][r * 256]);
        }
        __syncthreads();
        for (int ch = 0; ch < NCH; ++ch) {
            int cur = ch & 1;
            if (ch + 1 < NCH) {
                int kc = (ch + 1) * 256;
                for (int rr = 0; rr < 8; ++rr) {
                    int r = wave * 8 + rr;
                    if (r < n) gload_lds16(base + (size_t)r * rstride + kc + ((lane ^ (r & 7)) << 2),
                                           &buf[cur ^ 1][r * 256]);
                }
            }
#pragma unroll
            for (int k2 = 0; k2 < 2; ++k2) {
                int q0 = (wave * 2 + k2) * 8 + fq * 2;
                float4 u0 = *(const float4*)&buf[cur][fr * 256 + ((q0 ^ s) << 2)];
                float4 u1 = *(const float4*)&buf[cur][fr * 256 + (((q0 + 1) ^ s) << 2)];
                float4 v0 = *(const float4*)&buf[cur][(16 + fr) * 256 + ((q0 ^ s) << 2)];
                float4 v1 = *(const float4*)&buf[cur][(16 + fr) * 256 + (((q0 + 1) ^ s) << 2)];
                bf16x8 af = { f2bf(u0.x), f2bf(u0.y), f2bf(u0.z), f2bf(u0.w),
                              f2bf(u1.x), f2bf(u1.y), f2bf(u1.z), f2bf(u1.w) };
                bf16x8 bf = { f2bf(v0.x), f2bf(v0.y), f2bf(v0.z), f2bf(v0.w),
                              f2bf(v1.x), f2bf(v1.y), f2bf(v1.z), f2bf(v1.w) };
                a00 = __builtin_amdgcn_mfma_f32_16x16x32_bf16(af, af, a00, 0, 0, 0);
                a01 = __builtin_amdgcn_mfma_f32_16x16x32_bf16(af, bf, a01, 0, 0, 0);
                a11 = __builtin_amdgcn_mfma_f32_16x16x32_bf16(bf, bf, a11, 0, 0, 0);
            }
            __syncthreads();
        }
        red[0][wave][lane] = a00;
        red[1][wave][lane] = a01;
        red[2][wave][lane] = a11;
        __syncthreads();
        if (wave < 3) {
            f32x4 s4 = red[wave][0][lane] + red[wave][1][lane] +
                       red[wave][2][lane] + red[wave][3][lane];
#pragma unroll
            for (int q = 0; q < 4; ++q) {
                int il = fq * 4 + q, jl = fr;
                int i = (wave == 2) ? 16 + il : il;
                int j = (wave == 0) ? jl : 16 + jl;
                if (i < n && j < n) {
                    int p = pairBase[g0 + i] + j;
                    if (p < strideP) relbuf[(size_t)c * strideP + p] = s4[q] * INV_NORM;
                    if (wave == 1) {   // mirror (symmetric)
                        int p2 = pairBase[g0 + j] + i;
                        if (p2 < strideP) relbuf[(size_t)c * strideP + p2] = s4[q] * INV_NORM;
                    }
                }
            }
        }
    } else {
        // generic fallback (statistically unreachable): tile pairs, single buffer
        for (int ti = 0; ti < nt; ++ti)
            for (int tj = ti; tj < nt; ++tj) {
                bool diag = (ti == tj);
                f32x4 acc = {0.f, 0.f, 0.f, 0.f};
                for (int ch = 0; ch < NCH; ++ch) {
                    int kc = ch * 256;
                    __syncthreads();
                    for (int rr = 0; rr < 4; ++rr) {
                        int rl = wave * 4 + rr;
                        int rgi = ti * 16 + rl;
                        if (rgi < n) gload_lds16(base + (size_t)rgi * rstride + kc + ((lane ^ (rl & 7)) << 2),
                                                 &buf[0][rl * 256]);
                        if (!diag) {
                            int rgj = tj * 16 + rl;
                            if (rgj < n) gload_lds16(base + (size_t)rgj * rstride + kc + ((lane ^ (rl & 7)) << 2),
                                                     &buf[0][(16 + rl) * 256]);
                        }
                    }
                    __syncthreads();
#pragma unroll
                    for (int k2 = 0; k2 < 2; ++k2) {
                        int q0 = (wave * 2 + k2) * 8 + fq * 2;
                        float4 u0 = *(const float4*)&buf[0][fr * 256 + ((q0 ^ s) << 2)];
                        float4 u1 = *(const float4*)&buf[0][fr * 256 + (((q0 + 1) ^ s) << 2)];
                        bf16x8 af = { f2bf(u0.x), f2bf(u0.y), f2bf(u0.z), f2bf(u0.w),
                                      f2bf(u1.x), f2bf(u1.y), f2bf(u1.z), f2bf(u1.w) };
                        bf16x8 bf = af;
                        if (!diag) {
                            float4 v0 = *(const float4*)&buf[0][(16 + fr) * 256 + ((q0 ^ s) << 2)];
                            float4 v1 = *(const float4*)&buf[0][(16 + fr) * 256 + (((q0 + 1) ^ s) << 2)];
                            bf16x8 bb = { f2bf(v0.x), f2bf(v0.y), f2bf(v0.z), f2bf(v0.w),
                                          f2bf(v1.x), f2bf(v1.y), f2bf(v1.z), f2bf(v1.w) };
                            bf = bb;
                        }
                        acc = __builtin_amdgcn_mfma_f32_16x16x32_bf16(af, bf, acc, 0, 0, 0);
                    }
                }
                __syncthreads();
                red[0][wave][lane] = acc;
                __syncthreads();
                if (wave == 0) {
                    f32x4 s4 = red[0][0][lane] + red[0][1][lane] + red[0][2][lane] + red[0][3][lane];
#pragma unroll
                    for (int q = 0; q < 4; ++q) {
                        int i = ti * 16 + fq * 4 + q, j = tj * 16 + fr;
                        if (i < n && j < n) {
                            int p = pairBase[g0 + i] + j;
                            if (p < strideP) relbuf[(size_t)c * strideP + p] = s4[q] * INV_NORM;
                            if (!diag) {
                                int p2 = pairBase[g0 + j] + i;
                                if (p2 < strideP) relbuf[(size_t)c * strideP + p2] = s4[q] * INV_NORM;
                            }
                        }
                    }
                }
                __syncthreads();
            }
    }
}

// softmax over channels, tiled transpose for coalescing; adds param term
__global__ __launch_bounds__(256) void k_softmax(float* __restrict__ relbuf,
                                                 const float* __restrict__ param,
                                                 const int* __restrict__ wsI, int strideP) {
    int np = wsI[33];
    if (np > strideP) np = strideP;
    int p0 = blockIdx.x * 64;
    if (p0 >= np) return;
    int nv = min(64, np - p0);
    __shared__ float tile[CC][68];   // 8.7 KB
    int t = threadIdx.x;
    for (int idx = t; idx < CC * 16; idx += 256) {
        int c = idx >> 4, q4 = (idx & 15) * 4;
        if (q4 + 4 <= nv) {
            *(float4*)&tile[c][q4] = *(const float4*)&relbuf[(size_t)c * strideP + p0 + q4];
        } else {
#pragma unroll
            for (int e = 0; e < 4; ++e)
                if (q4 + e < nv) tile[c][q4 + e] = relbuf[(size_t)c * strideP + p0 + q4 + e];
        }
    }
    __syncthreads();
    if (t < 64 && t < nv) {
        int p = p0 + t;
        const int* pairBase = wsI + 1088;
        int lo = 0, hi = PP - 1;
        while (lo < hi) { int mid = (lo + hi + 1) >> 1; if (pairBase[mid] <= p) lo = mid; else hi = mid - 1; }
        int i = lo;
        int j = wsI[64 + i] + (p - pairBase[i]);
        float pd = 0.f;
#pragma unroll
        for (int k = 0; k < PDIMK; ++k) pd += param[i * PDIMK + k] * param[j * PDIMK + k];
        pd *= INV_PNORM;
        float mx = -3.4e38f;
#pragma unroll
        for (int c = 0; c < CC; ++c) mx = fmaxf(mx, tile[c][t] + pd);
        float ssum = 0.f;
#pragma unroll
        for (int c = 0; c < CC; ++c) { float e = __expf(tile[c][t] + pd - mx); tile[c][t] = e; ssum += e; }
        float inv = 1.0f / ssum;
#pragma unroll
        for (int c = 0; c < CC; ++c) tile[c][t] *= inv;
    }
    __syncthreads();
    for (int idx = t; idx < CC * 16; idx += 256) {
        int c = idx >> 4, q4 = (idx & 15) * 4;
        if (q4 + 4 <= nv) {
            *(float4*)&relbuf[(size_t)c * strideP + p0 + q4] = *(const float4*)&tile[c][q4];
        } else {
#pragma unroll
            for (int e = 0; e < 4; ++e)
                if (q4 + e < nv) relbuf[(size_t)c * strideP + p0 + q4 + e] = tile[c][q4 + e];
        }
    }
}

// out[i,c,d] = relu( sum_j (att[c,i,j] + delta_ij) * x[j,c,d] )
// Uniform 16x16 chunked structure. Per jc-chunk: preload ALL 16 j-rows into
// registers UNCONDITIONALLY (clamped index -> no exec-masked loads; rows >= n
// get real data x att=0) -> 16 independent loads in flight per wave.
// att_t 16x16 zero-padded, filled 1:1 by 256 threads. NT stores.
__global__ __launch_bounds__(256) void k_out(const float* __restrict__ feats,
                                             const float* __restrict__ att,
                                             const int* __restrict__ wsI,
                                             float* __restrict__ out, int strideP) {
    __shared__ float att_t[16][20];    // [jj][ii], 1.25 KB
    int m = blockIdx.x, c = blockIdx.y;
    int g0 = wsI[m], n = wsI[m + 1] - g0;
    if (n <= 0) return;
    const int* pairBase = wsI + 1088;
    int t = threadIdx.x;
    int col = blockIdx.z * 1024 + t * 4;
    const size_t rs = (size_t)CC * HWD;                     // row stride (floats)
    const float* fb = feats + ((size_t)g0 * CC + c) * HWD + col;
    float*       ob = out   + ((size_t)g0 * CC + c) * HWD + col;
    int ii_ = t & 15, jj_ = t >> 4;     // att staging: 256 threads = 16x16 tile

    for (int ic = 0; ic < n; ic += 16) {
        float4 acc[16];
#pragma unroll
        for (int q = 0; q < 16; ++q) acc[q] = make_float4(0.f, 0.f, 0.f, 0.f);
        for (int jc = 0; jc < n; jc += 16) {
            // preload all 16 rows of this jc chunk, unconditional (clamped)
            float4 xr[16];
#pragma unroll
            for (int p = 0; p < 16; ++p) {
                int r = jc + p; if (r >= n) r = n - 1;
                xr[p] = *(const float4*)(fb + (size_t)r * rs);
            }
            __syncthreads();   // previous FMA done reading att_t
            {
                float a = 0.f;
                int gi = ic + ii_, gj = jc + jj_;
                if (gi < n && gj < n) {
                    int p = pairBase[g0 + gi] + gj;
                    if (p < strideP) a = att[(size_t)c * strideP + p];
                    if (gi == gj) a += 1.0f;   // residual folded in
                }
                att_t[jj_][ii_] = a;
            }
            __syncthreads();   // att_t ready
#pragma unroll
            for (int jj = 0; jj < 16; ++jj) {
                float4 vj = xr[jj];
                float4 a0 = *(const float4*)&att_t[jj][0];   // broadcast reads
                float4 a1 = *(const float4*)&att_t[jj][4];
                float4 a2 = *(const float4*)&att_t[jj][8];
                float4 a3 = *(const float4*)&att_t[jj][12];
                acc[0].x  += a0.x * vj.x; acc[0].y  += a0.x * vj.y; acc[0].z  += a0.x * vj.z; acc[0].w  += a0.x * vj.w;
                acc[1].x  += a0.y * vj.x; acc[1].y  += a0.y * vj.y; acc[1].z  += a0.y * vj.z; acc[1].w  += a0.y * vj.w;
                acc[2].x  += a0.z * vj.x; acc[2].y  += a0.z * vj.y; acc[2].z  += a0.z * vj.z; acc[2].w  += a0.z * vj.w;
                acc[3].x  += a0.w * vj.x; acc[3].y  += a0.w * vj.y; acc[3].z  += a0.w * vj.z; acc[3].w  += a0.w * vj.w;
                acc[4].x  += a1.x * vj.x; acc[4].y  += a1.x * vj.y; acc[4].z  += a1.x * vj.z; acc[4].w  += a1.x * vj.w;
                acc[5].x  += a1.y * vj.x; acc[5].y  += a1.y * vj.y; acc[5].z  += a1.y * vj.z; acc[5].w  += a1.y * vj.w;
                acc[6].x  += a1.z * vj.x; acc[6].y  += a1.z * vj.y; acc[6].z  += a1.z * vj.z; acc[6].w  += a1.z * vj.w;
                acc[7].x  += a1.w * vj.x; acc[7].y  += a1.w * vj.y; acc[7].z  += a1.w * vj.z; acc[7].w  += a1.w * vj.w;
                acc[8].x  += a2.x * vj.x; acc[8].y  += a2.x * vj.y; acc[8].z  += a2.x * vj.z; acc[8].w  += a2.x * vj.w;
                acc[9].x  += a2.y * vj.x; acc[9].y  += a2.y * vj.y; acc[9].z  += a2.y * vj.z; acc[9].w  += a2.y * vj.w;
                acc[10].x += a2.z * vj.x; acc[10].y += a2.z * vj.y; acc[10].z += a2.z * vj.z; acc[10].w += a2.z * vj.w;
                acc[11].x += a2.w * vj.x; acc[11].y += a2.w * vj.y; acc[11].z += a2.w * vj.z; acc[11].w += a2.w * vj.w;
                acc[12].x += a3.x * vj.x; acc[12].y += a3.x * vj.y; acc[12].z += a3.x * vj.z; acc[12].w += a3.x * vj.w;
                acc[13].x += a3.y * vj.x; acc[13].y += a3.y * vj.y; acc[13].z += a3.y * vj.z; acc[13].w += a3.y * vj.w;
                acc[14].x += a3.z * vj.x; acc[14].y += a3.z * vj.y; acc[14].z += a3.z * vj.z; acc[14].w += a3.z * vj.w;
                acc[15].x += a3.w * vj.x; acc[15].y += a3.w * vj.y; acc[15].z += a3.w * vj.z; acc[15].w += a3.w * vj.w;
            }
        }
#pragma unroll
        for (int ii = 0; ii < 16; ++ii) {
            if (ic + ii < n) {
                float4 r = acc[ii];
                f32x4 rv = { fmaxf(r.x, 0.f), fmaxf(r.y, 0.f),
                             fmaxf(r.z, 0.f), fmaxf(r.w, 0.f) };
                __builtin_nontemporal_store(rv, (f32x4*)&ob[(size_t)(ic + ii) * rs]);
            }
        }
    }
}

extern "C" void kernel_launch(void* const* d_in, const int* in_sizes, int n_in,
                              void* d_out, int out_size, void* d_ws, size_t ws_size,
                              hipStream_t stream) {
    const float* feats = (const float*)d_in[0];
    const int*   imgid = (const int*)d_in[1];
    const float* param = (const float*)d_in[2];
    float* out = (float*)d_out;
    int* wsI = (int*)d_ws;
    float* relbuf = (float*)((char*)d_ws + 8192);

    long capL = ((long)ws_size - 8192) / (CC * 4);
    if (capL < 0) capL = 0;
    if (capL > (long)PP * PP) capL = (long)PP * PP;
    int strideP = (int)capL;

    k_groups<<<1, PP, 0, stream>>>(imgid, wsI);
    k_rel<<<dim3(NIMG, CC), 256, 0, stream>>>(feats, wsI, relbuf, strideP);
    k_softmax<<<dim3((PP * PP + 63) / 64), 256, 0, stream>>>(relbuf, param, wsI, strideP);
    k_out<<<dim3(NIMG, CC, 3), 256, 0, stream>>>(feats, relbuf, wsI, out, strideP);
}

// Round 17
// 135.778 us; speedup vs baseline: 1.2223x; 1.2223x over previous
//
#include <hip/hip_runtime.h>
#include <hip/hip_bf16.h>

#define PP   512
#define CC   32
#define HWD  3072           // 64*48
#define PDIMK 34
#define NIMG 32
#define NCH  (HWD / 256)    // 12 K-chunks of 256 floats

static constexpr float INV_NORM  = 1.0f / 96.0f;
static constexpr float INV_PNORM = 1.0f / 480.0f;

typedef short bf16x8 __attribute__((ext_vector_type(8)));
typedef float f32x4  __attribute__((ext_vector_type(4)));

__device__ __forceinline__ short f2bf(float f) {   // RNE fp32 -> bf16 bits
    __hip_bfloat16 h = __float2bfloat16(f);
    return *reinterpret_cast<short*>(&h);
}

// async global->LDS, 16B per lane: dest = lds + lane*16 (linear), src per-lane
__device__ __forceinline__ void gload_lds16(const float* g, float* l) {
    __builtin_amdgcn_global_load_lds(
        (const __attribute__((address_space(1))) void*)g,
        (__attribute__((address_space(3))) void*)l, 16, 0, 0);
}

// workspace int layout:
// [0..32] gstart  [33] npairs  [64..575] start[i]  [576..1087] cnt[i]
// [1088..1599] pairBase[i]   byte 8192+: rel/att buffer [c][strideP] floats

__global__ void k_groups(const int* __restrict__ imgid, int* __restrict__ wsI) {
    __shared__ int s_img[PP];
    __shared__ int s_cnt[PP];
    int t = threadIdx.x;
    s_img[t] = imgid[t];
    __syncthreads();
    int v = s_img[t];
    int lo = 0, hi = PP;
    while (lo < hi) { int mid = (lo + hi) >> 1; if (s_img[mid] < v) lo = mid + 1; else hi = mid; }
    int st = lo;
    lo = 0; hi = PP;
    while (lo < hi) { int mid = (lo + hi) >> 1; if (s_img[mid] <= v) lo = mid + 1; else hi = mid; }
    int cn = lo - st;
    wsI[64 + t]  = st;
    wsI[576 + t] = cn;
    s_cnt[t] = cn;
    if (t <= NIMG) {
        lo = 0; hi = PP;
        while (lo < hi) { int mid = (lo + hi) >> 1; if (s_img[mid] < t) lo = mid + 1; else hi = mid; }
        wsI[t] = lo;
    }
    __syncthreads();
    if (t == 0) {
        int acc = 0;
        for (int i = 0; i < PP; ++i) { wsI[1088 + i] = acc; acc += s_cnt[i]; }
        wsI[33] = acc;
    }
}

// rel[c][p(i,j)] = dot(x[c,i,:], x[c,j,:]) / 96   (transposed layout)
// global_load_lds staging (dense 1KB/row bursts, fire-and-forget), XOR-swizzle
// applied to SOURCE (linear LDS dest) and to frag reads -> conflict-free.
// K split across 4 waves (one f32x4 acc per tile per wave), LDS reduce.
// Grid (image, channel), block 256 = 4 waves.
__global__ __launch_bounds__(256) void k_rel(const float* __restrict__ feats,
                                             const int* __restrict__ wsI,
                                             float* __restrict__ relbuf, int strideP) {
    __shared__ float buf[2][32 * 256];   // 64 KB (2 chunks x 32 rows x 1KB)
    __shared__ f32x4 red[3][4][64];      // 12 KB reduce scratch
    int m = blockIdx.x, c = blockIdx.y;
    int g0 = wsI[m], n = wsI[m + 1] - g0;
    if (n <= 0) return;
    const int* pairBase = wsI + 1088;
    int t = threadIdx.x, wave = t >> 6, lane = t & 63;
    int fr = lane & 15, fq = lane >> 4;
    const size_t rstride = (size_t)CC * HWD;
    const float* base = feats + ((size_t)g0 * CC + c) * HWD;
    int nt = (n + 15) >> 4;
    int s = fr & 7;                       // read-side XOR (row&7; (16+fr)&7 == fr&7)

    if (nt == 1) {
        f32x4 acc = {0.f, 0.f, 0.f, 0.f};
        for (int rr = 0; rr < 4; ++rr) {
            int r = wave * 4 + rr;
            if (r < n) gload_lds16(base + (size_t)r * rstride + ((lane ^ (r & 7)) << 2),
                                   &buf[0][r * 256]);
        }
        __syncthreads();
        for (int ch = 0; ch < NCH; ++ch) {
            int cur = ch & 1;
            if (ch + 1 < NCH) {
                int kc = (ch + 1) * 256;
                for (int rr = 0; rr < 4; ++rr) {
                    int r = wave * 4 + rr;
                    if (r < n) gload_lds16(base + (size_t)r * rstride + kc + ((lane ^ (r & 7)) << 2),
                                           &buf[cur ^ 1][r * 256]);
                }
            }
#pragma unroll
            for (int k2 = 0; k2 < 2; ++k2) {
                int q0 = (wave * 2 + k2) * 8 + fq * 2;
                float4 f0 = *(const float4*)&buf[cur][fr * 256 + ((q0 ^ s) << 2)];
                float4 f1 = *(const float4*)&buf[cur][fr * 256 + (((q0 + 1) ^ s) << 2)];
                bf16x8 af = { f2bf(f0.x), f2bf(f0.y), f2bf(f0.z), f2bf(f0.w),
                              f2bf(f1.x), f2bf(f1.y), f2bf(f1.z), f2bf(f1.w) };
                acc = __builtin_amdgcn_mfma_f32_16x16x32_bf16(af, af, acc, 0, 0, 0);
            }
            __syncthreads();
        }
        red[0][wave][lane] = acc;
        __syncthreads();
        if (wave == 0) {
            f32x4 s4 = red[0][0][lane] + red[0][1][lane] + red[0][2][lane] + red[0][3][lane];
#pragma unroll
            for (int q = 0; q < 4; ++q) {
                int i = fq * 4 + q, j = fr;          // C/D map (HW-verified)
                if (i < n && j < n) {
                    int p = pairBase[g0 + i] + j;
                    if (p < strideP) relbuf[(size_t)c * strideP + p] = s4[q] * INV_NORM;
                }
            }
        }
    } else if (nt == 2) {
        f32x4 a00 = {0.f,0.f,0.f,0.f}, a01 = a00, a11 = a00;
        for (int rr = 0; rr < 8; ++rr) {
            int r = wave * 8 + rr;
            if (r < n) gload_lds16(base + (size_t)r * rstride + ((lane ^ (r & 7)) << 2),
                                   &buf[0][r * 256]);
        }
        __syncthreads();
        for (int ch = 0; ch < NCH; ++ch) {
            int cur = ch & 1;
            if (ch + 1 < NCH) {
                int kc = (ch + 1) * 256;
                for (int rr = 0; rr < 8; ++rr) {
                    int r = wave * 8 + rr;
                    if (r < n) gload_lds16(base + (size_t)r * rstride + kc + ((lane ^ (r & 7)) << 2),
                                           &buf[cur ^ 1][r * 256]);
                }
            }
#pragma unroll
            for (int k2 = 0; k2 < 2; ++k2) {
                int q0 = (wave * 2 + k2) * 8 + fq * 2;
                float4 u0 = *(const float4*)&buf[cur][fr * 256 + ((q0 ^ s) << 2)];
                float4 u1 = *(const float4*)&buf[cur][fr * 256 + (((q0 + 1) ^ s) << 2)];
                float4 v0 = *(const float4*)&buf[cur][(16 + fr) * 256 + ((q0 ^ s) << 2)];
                float4 v1 = *(const float4*)&buf[cur][(16 + fr) * 256 + (((q0 + 1) ^ s) << 2)];
                bf16x8 af = { f2bf(u0.x), f2bf(u0.y), f2bf(u0.z), f2bf(u0.w),
                              f2bf(u1.x), f2bf(u1.y), f2bf(u1.z), f2bf(u1.w) };
                bf16x8 bf = { f2bf(v0.x), f2bf(v0.y), f2bf(v0.z), f2bf(v0.w),
                              f2bf(v1.x), f2bf(v1.y), f2bf(v1.z), f2bf(v1.w) };
                a00 = __builtin_amdgcn_mfma_f32_16x16x32_bf16(af, af, a00, 0, 0, 0);
                a01 = __builtin_amdgcn_mfma_f32_16x16x32_bf16(af, bf, a01, 0, 0, 0);
                a11 = __builtin_amdgcn_mfma_f32_16x16x32_bf16(bf, bf, a11, 0, 0, 0);
            }
            __syncthreads();
        }
        red[0][wave][lane] = a00;
        red[1][wave][lane] = a01;
        red[2][wave][lane] = a11;
        __syncthreads();
        if (wave < 3) {
            f32x4 s4 = red[wave][0][lane] + red[wave][1][lane] +
                       red[wave][2][lane] + red[wave][3][lane];
#pragma unroll
            for (int q = 0; q < 4; ++q) {
                int il = fq * 4 + q, jl = fr;
                int i = (wave == 2) ? 16 + il : il;
                int j = (wave == 0) ? jl : 16 + jl;
                if (i < n && j < n) {
                    int p = pairBase[g0 + i] + j;
                    if (p < strideP) relbuf[(size_t)c * strideP + p] = s4[q] * INV_NORM;
                    if (wave == 1) {   // mirror (symmetric)
                        int p2 = pairBase[g0 + j] + i;
                        if (p2 < strideP) relbuf[(size_t)c * strideP + p2] = s4[q] * INV_NORM;
                    }
                }
            }
        }
    } else {
        // generic fallback (statistically unreachable): tile pairs, single buffer
        for (int ti = 0; ti < nt; ++ti)
            for (int tj = ti; tj < nt; ++tj) {
                bool diag = (ti == tj);
                f32x4 acc = {0.f, 0.f, 0.f, 0.f};
                for (int ch = 0; ch < NCH; ++ch) {
                    int kc = ch * 256;
                    __syncthreads();
                    for (int rr = 0; rr < 4; ++rr) {
                        int rl = wave * 4 + rr;
                        int rgi = ti * 16 + rl;
                        if (rgi < n) gload_lds16(base + (size_t)rgi * rstride + kc + ((lane ^ (rl & 7)) << 2),
                                                 &buf[0][rl * 256]);
                        if (!diag) {
                            int rgj = tj * 16 + rl;
                            if (rgj < n) gload_lds16(base + (size_t)rgj * rstride + kc + ((lane ^ (rl & 7)) << 2),
                                                     &buf[0][(16 + rl) * 256]);
                        }
                    }
                    __syncthreads();
#pragma unroll
                    for (int k2 = 0; k2 < 2; ++k2) {
                        int q0 = (wave * 2 + k2) * 8 + fq * 2;
                        float4 u0 = *(const float4*)&buf[0][fr * 256 + ((q0 ^ s) << 2)];
                        float4 u1 = *(const float4*)&buf[0][fr * 256 + (((q0 + 1) ^ s) << 2)];
                        bf16x8 af = { f2bf(u0.x), f2bf(u0.y), f2bf(u0.z), f2bf(u0.w),
                                      f2bf(u1.x), f2bf(u1.y), f2bf(u1.z), f2bf(u1.w) };
                        bf16x8 bf = af;
                        if (!diag) {
                            float4 v0 = *(const float4*)&buf[0][(16 + fr) * 256 + ((q0 ^ s) << 2)];
                            float4 v1 = *(const float4*)&buf[0][(16 + fr) * 256 + (((q0 + 1) ^ s) << 2)];
                            bf16x8 bb = { f2bf(v0.x), f2bf(v0.y), f2bf(v0.z), f2bf(v0.w),
                                          f2bf(v1.x), f2bf(v1.y), f2bf(v1.z), f2bf(v1.w) };
                            bf = bb;
                        }
                        acc = __builtin_amdgcn_mfma_f32_16x16x32_bf16(af, bf, acc, 0, 0, 0);
                    }
                }
                __syncthreads();
                red[0][wave][lane] = acc;
                __syncthreads();
                if (wave == 0) {
                    f32x4 s4 = red[0][0][lane] + red[0][1][lane] + red[0][2][lane] + red[0][3][lane];
#pragma unroll
                    for (int q = 0; q < 4; ++q) {
                        int i = ti * 16 + fq * 4 + q, j = tj * 16 + fr;
                        if (i < n && j < n) {
                            int p = pairBase[g0 + i] + j;
                            if (p < strideP) relbuf[(size_t)c * strideP + p] = s4[q] * INV_NORM;
                            if (!diag) {
                                int p2 = pairBase[g0 + j] + i;
                                if (p2 < strideP) relbuf[(size_t)c * strideP + p2] = s4[q] * INV_NORM;
                            }
                        }
                    }
                }
                __syncthreads();
            }
    }
}

// softmax over channels, tiled transpose for coalescing; adds param term
__global__ __launch_bounds__(256) void k_softmax(float* __restrict__ relbuf,
                                                 const float* __restrict__ param,
                                                 const int* __restrict__ wsI, int strideP) {
    int np = wsI[33];
    if (np > strideP) np = strideP;
    int p0 = blockIdx.x * 64;
    if (p0 >= np) return;
    int nv = min(64, np - p0);
    __shared__ float tile[CC][68];   // 8.7 KB
    int t = threadIdx.x;
    for (int idx = t; idx < CC * 16; idx += 256) {
        int c = idx >> 4, q4 = (idx & 15) * 4;
        if (q4 + 4 <= nv) {
            *(float4*)&tile[c][q4] = *(const float4*)&relbuf[(size_t)c * strideP + p0 + q4];
        } else {
#pragma unroll
            for (int e = 0; e < 4; ++e)
                if (q4 + e < nv) tile[c][q4 + e] = relbuf[(size_t)c * strideP + p0 + q4 + e];
        }
    }
    __syncthreads();
    if (t < 64 && t < nv) {
        int p = p0 + t;
        const int* pairBase = wsI + 1088;
        int lo = 0, hi = PP - 1;
        while (lo < hi) { int mid = (lo + hi + 1) >> 1; if (pairBase[mid] <= p) lo = mid; else hi = mid - 1; }
        int i = lo;
        int j = wsI[64 + i] + (p - pairBase[i]);
        float pd = 0.f;
#pragma unroll
        for (int k = 0; k < PDIMK; ++k) pd += param[i * PDIMK + k] * param[j * PDIMK + k];
        pd *= INV_PNORM;
        float mx = -3.4e38f;
#pragma unroll
        for (int c = 0; c < CC; ++c) mx = fmaxf(mx, tile[c][t] + pd);
        float ssum = 0.f;
#pragma unroll
        for (int c = 0; c < CC; ++c) { float e = __expf(tile[c][t] + pd - mx); tile[c][t] = e; ssum += e; }
        float inv = 1.0f / ssum;
#pragma unroll
        for (int c = 0; c < CC; ++c) tile[c][t] *= inv;
    }
    __syncthreads();
    for (int idx = t; idx < CC * 16; idx += 256) {
        int c = idx >> 4, q4 = (idx & 15) * 4;
        if (q4 + 4 <= nv) {
            *(float4*)&relbuf[(size_t)c * strideP + p0 + q4] = *(const float4*)&tile[c][q4];
        } else {
#pragma unroll
            for (int e = 0; e < 4; ++e)
                if (q4 + e < nv) relbuf[(size_t)c * strideP + p0 + q4 + e] = tile[c][q4 + e];
        }
    }
}

// out[i,c,d] = relu( sum_j (att[c,i,j] + delta_ij) * x[j,c,d] )
// R11 structure (best measured): MLP-4 register pipeline. NT stores: output
// is write-once, bypassing L2 preserves residency for latency-critical reads.
__global__ __launch_bounds__(256) void k_out(const float* __restrict__ feats,
                                             const float* __restrict__ att,
                                             const int* __restrict__ wsI,
                                             float* __restrict__ out, int strideP) {
    __shared__ float att_t[32][20];    // [jj][ii], 2.5 KB
    int m = blockIdx.x, c = blockIdx.y;
    int g0 = wsI[m], n = wsI[m + 1] - g0;
    if (n <= 0) return;
    const int* pairBase = wsI + 1088;
    int t = threadIdx.x;
    int col = blockIdx.z * 1024 + t * 4;
    const size_t rs = (size_t)CC * HWD;                     // row stride (floats)
    const float* fb = feats + ((size_t)g0 * CC + c) * HWD + col;
    float*       ob = out   + ((size_t)g0 * CC + c) * HWD + col;

    for (int ic = 0; ic < n; ic += 16) {
        int ni = min(16, n - ic);
        float4 acc[16];
#pragma unroll
        for (int q = 0; q < 16; ++q) acc[q] = make_float4(0.f, 0.f, 0.f, 0.f);
        for (int jc = 0; jc < n; jc += 32) {
            int nj = min(32, n - jc);
            __syncthreads();
            for (int idx = t; idx < 512; idx += 256) {      // 32 jj x 16 ii
                int jj = idx & 31, ii = idx >> 5;
                float a = 0.f;
                if (ii < ni && jj < nj) {
                    int p = pairBase[g0 + ic + ii] + jc + jj;
                    if (p < strideP) a = att[(size_t)c * strideP + p];
                    if (ic + ii == jc + jj) a += 1.0f;      // residual folded in
                }
                att_t[jj][ii] = a;
            }
            __syncthreads();
            const float* fj = fb + (size_t)jc * rs;
            float4 vbuf[4];
#pragma unroll
            for (int k = 0; k < 4; ++k) {
                int r = (k < nj) ? k : nj - 1;
                vbuf[k] = *(const float4*)(fj + (size_t)r * rs);
            }
            for (int j0 = 0; j0 < nj; j0 += 4) {
                float4 vcur[4];
#pragma unroll
                for (int k = 0; k < 4; ++k) vcur[k] = vbuf[k];
#pragma unroll
                for (int k = 0; k < 4; ++k) {               // prefetch next batch
                    int r = j0 + 4 + k;
                    if (r < nj) vbuf[k] = *(const float4*)(fj + (size_t)r * rs);
                }
#pragma unroll
                for (int k = 0; k < 4; ++k) {
                    int jj = j0 + k;
                    if (jj < nj) {
                        float4 vj = vcur[k];
                        float4 a0 = *(const float4*)&att_t[jj][0];   // broadcast reads
                        float4 a1 = *(const float4*)&att_t[jj][4];
                        float4 a2 = *(const float4*)&att_t[jj][8];
                        float4 a3 = *(const float4*)&att_t[jj][12];
                        acc[0].x  += a0.x * vj.x; acc[0].y  += a0.x * vj.y; acc[0].z  += a0.x * vj.z; acc[0].w  += a0.x * vj.w;
                        acc[1].x  += a0.y * vj.x; acc[1].y  += a0.y * vj.y; acc[1].z  += a0.y * vj.z; acc[1].w  += a0.y * vj.w;
                        acc[2].x  += a0.z * vj.x; acc[2].y  += a0.z * vj.y; acc[2].z  += a0.z * vj.z; acc[2].w  += a0.z * vj.w;
                        acc[3].x  += a0.w * vj.x; acc[3].y  += a0.w * vj.y; acc[3].z  += a0.w * vj.z; acc[3].w  += a0.w * vj.w;
                        acc[4].x  += a1.x * vj.x; acc[4].y  += a1.x * vj.y; acc[4].z  += a1.x * vj.z; acc[4].w  += a1.x * vj.w;
                        acc[5].x  += a1.y * vj.x; acc[5].y  += a1.y * vj.y; acc[5].z  += a1.y * vj.z; acc[5].w  += a1.y * vj.w;
                        acc[6].x  += a1.z * vj.x; acc[6].y  += a1.z * vj.y; acc[6].z  += a1.z * vj.z; acc[6].w  += a1.z * vj.w;
                        acc[7].x  += a1.w * vj.x; acc[7].y  += a1.w * vj.y; acc[7].z  += a1.w * vj.z; acc[7].w  += a1.w * vj.w;
                        acc[8].x  += a2.x * vj.x; acc[8].y  += a2.x * vj.y; acc[8].z  += a2.x * vj.z; acc[8].w  += a2.x * vj.w;
                        acc[9].x  += a2.y * vj.x; acc[9].y  += a2.y * vj.y; acc[9].z  += a2.y * vj.z; acc[9].w  += a2.y * vj.w;
                        acc[10].x += a2.z * vj.x; acc[10].y += a2.z * vj.y; acc[10].z += a2.z * vj.z; acc[10].w += a2.z * vj.w;
                        acc[11].x += a2.w * vj.x; acc[11].y += a2.w * vj.y; acc[11].z += a2.w * vj.z; acc[11].w += a2.w * vj.w;
                        acc[12].x += a3.x * vj.x; acc[12].y += a3.x * vj.y; acc[12].z += a3.x * vj.z; acc[12].w += a3.x * vj.w;
                        acc[13].x += a3.y * vj.x; acc[13].y += a3.y * vj.y; acc[13].z += a3.y * vj.z; acc[13].w += a3.y * vj.w;
                        acc[14].x += a3.z * vj.x; acc[14].y += a3.z * vj.y; acc[14].z += a3.z * vj.z; acc[14].w += a3.z * vj.w;
                        acc[15].x += a3.w * vj.x; acc[15].y += a3.w * vj.y; acc[15].z += a3.w * vj.z; acc[15].w += a3.w * vj.w;
                    }
                }
            }
        }
#pragma unroll
        for (int ii = 0; ii < 16; ++ii) {
            if (ii < ni) {
                float4 r = acc[ii];
                f32x4 rv = { fmaxf(r.x, 0.f), fmaxf(r.y, 0.f),
                             fmaxf(r.z, 0.f), fmaxf(r.w, 0.f) };
                __builtin_nontemporal_store(rv, (f32x4*)&ob[(size_t)(ic + ii) * rs]);
            }
        }
    }
}

extern "C" void kernel_launch(void* const* d_in, const int* in_sizes, int n_in,
                              void* d_out, int out_size, void* d_ws, size_t ws_size,
                              hipStream_t stream) {
    const float* feats = (const float*)d_in[0];
    const int*   imgid = (const int*)d_in[1];
    const float* param = (const float*)d_in[2];
    float* out = (float*)d_out;
    int* wsI = (int*)d_ws;
    float* relbuf = (float*)((char*)d_ws + 8192);

    long capL = ((long)ws_size - 8192) / (CC * 4);
    if (capL < 0) capL = 0;
    if (capL > (long)PP * PP) capL = (long)PP * PP;
    int strideP = (int)capL;

    k_groups<<<1, PP, 0, stream>>>(imgid, wsI);
    k_rel<<<dim3(NIMG, CC), 256, 0, stream>>>(feats, wsI, relbuf, strideP);
    k_softmax<<<dim3((PP * PP + 63) / 64), 256, 0, stream>>>(relbuf, param, wsI, strideP);
    k_out<<<dim3(NIMG, CC, 3), 256, 0, stream>>>(feats, relbuf, wsI, out, strideP);
}